// Round 4
// baseline (62.183 us; speedup 1.0000x reference)
//
#include <hip/hip_runtime.h>
#include <hip/hip_bf16.h>

typedef unsigned short u16;
typedef unsigned int u32;
typedef __attribute__((ext_vector_type(8))) short bf16x8;
typedef __attribute__((ext_vector_type(4))) float f32x4;

#define S_LEN 2048
#define NHQ   16
#define NHKV  4
#define HD    64
#define KVBLK 64
#define QBLK  128
#define LPAD  72   // 144B row stride: conflict-optimal b128 reads (8 lanes/bank uniform)
// (1/sqrt(64)) * log2(e): QK^T lands in exp2 domain
#define QSCALE 0.18033688011112042f

__device__ __forceinline__ u32 cvt2(float lo, float hi) {
    __hip_bfloat162 h = __float22bfloat162_rn(make_float2(lo, hi));
    union { __hip_bfloat162 h; u32 u; } c; c.h = h; return c.u;   // v_cvt_pk_bf16_f32
}
__device__ __forceinline__ u16 cvt1(float x) {
    __hip_bfloat16 h = __float2bfloat16(x);
    union { __hip_bfloat16 h; u16 u; } c; c.h = h; return c.u;
}

__global__ __launch_bounds__(512, 4)
void gqa_fwd_kernel(const float* __restrict__ Qp, const float* __restrict__ Kp,
                    const float* __restrict__ Vp, float* __restrict__ Op)
{
    __shared__ __align__(16) u16 Kl[2][KVBLK][LPAD];  // K dbuf, [kv][d]
    __shared__ __align__(16) u16 Vt[2][HD][LPAD];     // V dbuf, transposed [dv][kv]
    __shared__ __align__(16) u16 Pl[8][16][LPAD];     // per-wave P, [q][kv]

    const int tid  = threadIdx.x;
    const int w    = tid >> 6;
    const int lane = tid & 63;
    const int l16  = lane & 15;
    const int quad = lane >> 4;

    // bid&7 -> (b,kvh): each XCD sees one K/V stream (L2 locality heuristic).
    // qt = 15 - (bid>>5): biggest blocks dispatch first (work ∝ 2qt+2).
    const int bid  = blockIdx.x;
    const int head = bid & 31;
    const int qt   = 15 - (bid >> 5);
    const int kvh  = head & 3;
    const int b    = (head >> 2) & 1;
    const int qh   = kvh * 4 + (head >> 3);

    const float* Kbase = Kp + (size_t)b * S_LEN * (NHKV*HD) + kvh*HD;
    const float* Vbase = Vp + (size_t)b * S_LEN * (NHKV*HD) + kvh*HD;
    const float* Qhead = Qp + (size_t)b * S_LEN * (NHQ*HD) + qh*HD;
    float*       Ohead = Op + (size_t)(b*NHQ + qh) * S_LEN * HD;

    const int q0    = qt * QBLK;
    const int nt    = 2*qt + 1;          // kv tiles 0..nt
    const int tlast = 2*qt + (w >> 2);   // waves 0-3 skip the last (fully masked) tile
    const int relq  = (w << 4) + l16;    // q row within the 128-row q-tile
    const int rk0w  = (w >> 2) << 6;     // diagonal sub-tile kv offset for this wave

    // staging maps (512 threads): K row-major coalesced; V transposed,
    // contiguous-row scalar b16 stores (2-way bank alias = free)
    const int krow = tid >> 4;          // 0..31, +32*i
    const int kc4  = (tid & 15) * 4;
    const int vrow = tid & 63;
    const int vc0  = w * 4;             // +32*i

    // ---- Q fragment (B operand of swapped QK^T), scale*log2e folded ----
    bf16x8 qf[2];
    {
        const float* qp = Qhead + (size_t)(q0 + relq) * (NHQ*HD);
        #pragma unroll
        for (int kk = 0; kk < 2; ++kk) {
            const float4 x = *(const float4*)(qp + kk*32 + quad*8);
            const float4 y = *(const float4*)(qp + kk*32 + quad*8 + 4);
            u32 tmp[4];
            tmp[0] = cvt2(x.x*QSCALE, x.y*QSCALE);
            tmp[1] = cvt2(x.z*QSCALE, x.w*QSCALE);
            tmp[2] = cvt2(y.x*QSCALE, y.y*QSCALE);
            tmp[3] = cvt2(y.z*QSCALE, y.w*QSCALE);
            qf[kk] = *(bf16x8*)tmp;
        }
    }

    f32x4 oacc[4];   // O^T: oacc[nb][r] = O[q=l16][dv = nb*16 + quad*4 + r]
    #pragma unroll
    for (int nb = 0; nb < 4; ++nb) { oacc[nb][0]=0.f; oacc[nb][1]=0.f; oacc[nb][2]=0.f; oacc[nb][3]=0.f; }
    float m_s = -1e30f;   // running max for q = l16 (replicated across quads)
    float l_p = 0.f;      // PER-QUAD partial row-sum; cross-quad reduced in epilogue

    int cur = 0;

    // ---- prologue: stage tile 0 ----
    #pragma unroll
    for (int i = 0; i < 2; ++i) {
        const float4 kx = *(const float4*)(Kbase + (size_t)(krow + 32*i)*(NHKV*HD) + kc4);
        *(uint2*)(&Kl[0][krow + 32*i][kc4]) = make_uint2(cvt2(kx.x,kx.y), cvt2(kx.z,kx.w));
        const float4 vx = *(const float4*)(Vbase + (size_t)vrow*(NHKV*HD) + vc0 + 32*i);
        Vt[0][vc0+32*i+0][vrow] = cvt1(vx.x);
        Vt[0][vc0+32*i+1][vrow] = cvt1(vx.y);
        Vt[0][vc0+32*i+2][vrow] = cvt1(vx.z);
        Vt[0][vc0+32*i+3][vrow] = cvt1(vx.w);
    }
    __syncthreads();

    for (int t = 0; t <= nt; ++t) {
        const bool pf_on = (t < nt);

        // ---- issue prefetch for tile t+1 (consumed after compute) ----
        float4 kpf[2], vpf[2];
        if (pf_on) {
            const int t1 = (t+1) * KVBLK;
            #pragma unroll
            for (int i = 0; i < 2; ++i) {
                kpf[i] = *(const float4*)(Kbase + (size_t)(t1 + krow + 32*i)*(NHKV*HD) + kc4);
                vpf[i] = *(const float4*)(Vbase + (size_t)(t1 + vrow)*(NHKV*HD) + vc0 + 32*i);
            }
        }

        if (t <= tlast) {
            // ---- swapped QK^T: lane holds S[kv = nb*16+quad*4+r][q = l16] ----
            f32x4 s[4];
            #pragma unroll
            for (int nb = 0; nb < 4; ++nb) {
                f32x4 acc = {0.f,0.f,0.f,0.f};
                #pragma unroll
                for (int kk = 0; kk < 2; ++kk) {
                    bf16x8 kf = *(const bf16x8*)(&Kl[cur][nb*16 + l16][kk*32 + quad*8]);
                    acc = __builtin_amdgcn_mfma_f32_16x16x32_bf16(kf, qf[kk], acc, 0, 0, 0);
                }
                s[nb] = acc;
            }

            // ---- causal mask on the diagonal sub-tile ----
            if (t == tlast) {
                #pragma unroll
                for (int nb = 0; nb < 4; ++nb)
                    #pragma unroll
                    for (int r = 0; r < 4; ++r)
                        if (rk0w + nb*16 + quad*4 + r > relq) s[nb][r] = -1e30f;
            }

            // ---- online softmax (exp2 domain); only the max needs cross-quad ----
            float lmax = fmaxf(fmaxf(s[0][0], s[0][1]), fmaxf(s[0][2], s[0][3]));
            #pragma unroll
            for (int nb = 1; nb < 4; ++nb)
                lmax = fmaxf(lmax, fmaxf(fmaxf(s[nb][0], s[nb][1]), fmaxf(s[nb][2], s[nb][3])));
            lmax = fmaxf(lmax, __shfl_xor(lmax, 16));
            lmax = fmaxf(lmax, __shfl_xor(lmax, 32));

            const float mnew = fmaxf(m_s, lmax);
            const float cf   = __builtin_amdgcn_exp2f(m_s - mnew);
            m_s = mnew;

            float lsum = 0.f;
            #pragma unroll
            for (int nb = 0; nb < 4; ++nb)
                #pragma unroll
                for (int r = 0; r < 4; ++r) {
                    const float p = __builtin_amdgcn_exp2f(s[nb][r] - mnew);
                    s[nb][r] = p;
                    lsum += p;
                }
            l_p = l_p * cf + lsum;          // per-quad partial; reduced at the end

            // ---- rescale O^T (q = l16: lane-local, no shuffles) ----
            #pragma unroll
            for (int nb = 0; nb < 4; ++nb)
                #pragma unroll
                for (int r = 0; r < 4; ++r) oacc[nb][r] *= cf;

            // ---- P -> Pl (pk dword stores), read back as B-fragment ----
            #pragma unroll
            for (int nb = 0; nb < 4; ++nb) {
                *(u32*)(&Pl[w][l16][nb*16 + quad*4])     = cvt2(s[nb][0], s[nb][1]);
                *(u32*)(&Pl[w][l16][nb*16 + quad*4 + 2]) = cvt2(s[nb][2], s[nb][3]);
            }
            bf16x8 pfrag[2];
            #pragma unroll
            for (int kk = 0; kk < 2; ++kk)
                pfrag[kk] = *(const bf16x8*)(&Pl[w][l16][kk*32 + quad*8]);

            // ---- O^T += V^T P^T : A = Vt rows (dv), B = P cols (q=l16) ----
            #pragma unroll
            for (int nb = 0; nb < 4; ++nb) {
                #pragma unroll
                for (int kk = 0; kk < 2; ++kk) {
                    bf16x8 vf = *(const bf16x8*)(&Vt[cur][nb*16 + l16][kk*32 + quad*8]);
                    oacc[nb] = __builtin_amdgcn_mfma_f32_16x16x32_bf16(vf, pfrag[kk], oacc[nb], 0, 0, 0);
                }
            }
        }

        // ---- write prefetched tile to other buffer; one barrier/tile ----
        if (pf_on) {
            #pragma unroll
            for (int i = 0; i < 2; ++i) {
                *(uint2*)(&Kl[cur^1][krow + 32*i][kc4]) =
                    make_uint2(cvt2(kpf[i].x,kpf[i].y), cvt2(kpf[i].z,kpf[i].w));
                Vt[cur^1][vc0+32*i+0][vrow] = cvt1(vpf[i].x);
                Vt[cur^1][vc0+32*i+1][vrow] = cvt1(vpf[i].y);
                Vt[cur^1][vc0+32*i+2][vrow] = cvt1(vpf[i].z);
                Vt[cur^1][vc0+32*i+3][vrow] = cvt1(vpf[i].w);
            }
            __syncthreads();
            cur ^= 1;
        }
    }

    // ---- epilogue: reduce l across quads once; O^T store, float4, lane-local ----
    l_p += __shfl_xor(l_p, 16);
    l_p += __shfl_xor(l_p, 32);
    const float inv = 1.0f / l_p;

    float* ob = Ohead + (size_t)(q0 + relq) * HD;
    #pragma unroll
    for (int nb = 0; nb < 4; ++nb) {
        float4 o4;
        o4.x = oacc[nb][0] * inv;
        o4.y = oacc[nb][1] * inv;
        o4.z = oacc[nb][2] * inv;
        o4.w = oacc[nb][3] * inv;
        *(float4*)(ob + nb*16 + quad*4) = o4;
    }
}

extern "C" void kernel_launch(void* const* d_in, const int* in_sizes, int n_in,
                              void* d_out, int out_size, void* d_ws, size_t ws_size,
                              hipStream_t stream) {
    const float* Q = (const float*)d_in[0];
    const float* K = (const float*)d_in[1];
    const float* V = (const float*)d_in[2];
    // d_in[3] (tril mask) computed analytically, never read.
    float* O = (float*)d_out;
    gqa_fwd_kernel<<<dim3(512), dim3(512), 0, stream>>>(Q, K, V, O);
}

// Round 5
// 47.151 us; speedup vs baseline: 1.3188x; 1.3188x over previous
//
#include <hip/hip_runtime.h>
#include <hip/hip_bf16.h>

typedef unsigned short u16;
typedef unsigned int u32;
typedef __attribute__((ext_vector_type(8))) short bf16x8;
typedef __attribute__((ext_vector_type(4))) float f32x4;

#define S_LEN 2048
#define NHQ   16
#define NHKV  4
#define HD    64
#define KVBLK 64
#define QBLK  128
#define LPAD  72   // 144B row stride: 16B-aligned rows, 9x16B slots
// (1/sqrt(64)) * log2(e): QK^T lands in exp2 domain
#define QSCALE 0.18033688011112042f
#define DEFER_THR 8.0f   // skip max-reduce/rescale while tile max <= m_s + 8 (P <= 2^8)

__device__ __forceinline__ u32 cvt2(float lo, float hi) {
    __hip_bfloat162 h = __float22bfloat162_rn(make_float2(lo, hi));
    union { __hip_bfloat162 h; u32 u; } c; c.h = h; return c.u;   // v_cvt_pk_bf16_f32
}
__device__ __forceinline__ u16 cvt1(float x) {
    __hip_bfloat16 h = __float2bfloat16(x);
    union { __hip_bfloat16 h; u16 u; } c; c.h = h; return c.u;
}

__global__ __launch_bounds__(512, 2)
void gqa_fwd_kernel(const float* __restrict__ Qp, const float* __restrict__ Kp,
                    const float* __restrict__ Vp, float* __restrict__ Op)
{
    __shared__ __align__(16) u16 Kl[2][KVBLK][LPAD];  // K dbuf, [kv][d]
    __shared__ __align__(16) u16 Vt[2][HD][LPAD];     // V dbuf, transposed [dv][kv]
    __shared__ __align__(16) u16 Pl[8][16][LPAD];     // per-wave P, [q][kv]

    const int tid  = threadIdx.x;
    const int w    = tid >> 6;
    const int lane = tid & 63;
    const int l16  = lane & 15;
    const int quad = lane >> 4;

    // bid&7 -> (b,kvh): each XCD L2 sees one K/V stream. Pair {15-j, j}: 34 tiles/block.
    const int bid = blockIdx.x;
    const int kvh = bid & 3;
    const int b   = (bid >> 2) & 1;
    const int j   = (bid >> 3) & 7;
    const int g   = bid >> 6;
    const int qh  = kvh * 4 + g;

    const float* Kbase = Kp + (size_t)b * S_LEN * (NHKV*HD) + kvh*HD;
    const float* Vbase = Vp + (size_t)b * S_LEN * (NHKV*HD) + kvh*HD;
    const float* Qhead = Qp + (size_t)b * S_LEN * (NHQ*HD) + qh*HD;
    float*       Ohead = Op + (size_t)(b*NHQ + qh) * S_LEN * HD;

    // staging maps (512 threads): K row-major coalesced; V transposed,
    // contiguous-row scalar b16 stores (2-way bank alias = free)
    const int krow = tid >> 4;          // 0..31, +32*i
    const int kc4  = (tid & 15) * 4;
    const int vrow = tid & 63;
    const int vc0  = w * 4;             // +32*i

    const int relq = (w << 4) + l16;    // q row within q-tile
    const int rk0w = (w >> 2) << 6;     // diagonal sub-tile kv offset for this wave
    int cur = 0;

    #pragma unroll 1
    for (int pass = 0; pass < 2; ++pass) {
        const int qt = pass ? j : (15 - j);
        const int q0 = qt * QBLK;
        const int nt = 2*qt + 1;
        const int tlast = 2*qt + (w >> 2);    // waves 0-3 skip the final (fully masked) tile

        // ---- Q fragment (B operand of swapped QK^T), scale*log2e folded ----
        bf16x8 qf[2];
        {
            const float* qp = Qhead + (size_t)(q0 + relq) * (NHQ*HD);
            #pragma unroll
            for (int kk = 0; kk < 2; ++kk) {
                const float4 x = *(const float4*)(qp + kk*32 + quad*8);
                const float4 y = *(const float4*)(qp + kk*32 + quad*8 + 4);
                u32 tmp[4];
                tmp[0] = cvt2(x.x*QSCALE, x.y*QSCALE);
                tmp[1] = cvt2(x.z*QSCALE, x.w*QSCALE);
                tmp[2] = cvt2(y.x*QSCALE, y.y*QSCALE);
                tmp[3] = cvt2(y.z*QSCALE, y.w*QSCALE);
                qf[kk] = *(bf16x8*)tmp;
            }
        }

        f32x4 oacc[4];   // O^T: oacc[nb][r] = O[q=l16][dv = nb*16 + quad*4 + r]
        #pragma unroll
        for (int nb = 0; nb < 4; ++nb) { oacc[nb][0]=0.f; oacc[nb][1]=0.f; oacc[nb][2]=0.f; oacc[nb][3]=0.f; }
        float m_s = -1e30f;   // running max for q = l16 (wave-uniform across quads)
        float l_p = 0.f;      // per-quad partial row-sum; cross-quad reduced in epilogue

        // running prefetch pointers (advanced once per tile: no per-load index math)
        const float* kpt = Kbase + (size_t)(KVBLK + krow)*(NHKV*HD) + kc4;
        const float* vpt = Vbase + (size_t)(KVBLK + vrow)*(NHKV*HD) + vc0;

        __syncthreads();   // previous pass finished reading LDS
        // ---- prologue: stage KV tile 0 into buf cur ----
        {
            const float* kp0 = Kbase + (size_t)krow*(NHKV*HD) + kc4;
            const float* vp0 = Vbase + (size_t)vrow*(NHKV*HD) + vc0;
            #pragma unroll
            for (int i = 0; i < 2; ++i) {
                const float4 kx = *(const float4*)(kp0 + (size_t)(32*i)*(NHKV*HD));
                *(uint2*)(&Kl[cur][krow + 32*i][kc4]) = make_uint2(cvt2(kx.x,kx.y), cvt2(kx.z,kx.w));
                const float4 vx = *(const float4*)(vp0 + 32*i);
                Vt[cur][vc0+32*i+0][vrow] = cvt1(vx.x);
                Vt[cur][vc0+32*i+1][vrow] = cvt1(vx.y);
                Vt[cur][vc0+32*i+2][vrow] = cvt1(vx.z);
                Vt[cur][vc0+32*i+3][vrow] = cvt1(vx.w);
            }
        }
        __syncthreads();

        for (int t = 0; t <= nt; ++t) {
            const bool pf_on = (t < nt);

            // ---- issue prefetch for tile t+1 (consumed after compute) ----
            float4 kpf[2], vpf[2];
            if (pf_on) {
                #pragma unroll
                for (int i = 0; i < 2; ++i) {
                    kpf[i] = *(const float4*)(kpt + (size_t)(32*i)*(NHKV*HD));
                    vpf[i] = *(const float4*)(vpt + 32*i);
                }
            }

            if (t <= tlast) {
                // ---- swapped QK^T: lane holds S[kv = nb*16+quad*4+r][q = l16] ----
                f32x4 s[4];
                __builtin_amdgcn_s_setprio(1);
                #pragma unroll
                for (int nb = 0; nb < 4; ++nb) {
                    f32x4 acc = {0.f,0.f,0.f,0.f};
                    #pragma unroll
                    for (int kk = 0; kk < 2; ++kk) {
                        bf16x8 kf = *(const bf16x8*)(&Kl[cur][nb*16 + l16][kk*32 + quad*8]);
                        acc = __builtin_amdgcn_mfma_f32_16x16x32_bf16(kf, qf[kk], acc, 0, 0, 0);
                    }
                    s[nb] = acc;
                }
                __builtin_amdgcn_s_setprio(0);

                // ---- causal mask on the diagonal sub-tile ----
                if (t == tlast) {
                    #pragma unroll
                    for (int nb = 0; nb < 4; ++nb)
                        #pragma unroll
                        for (int r = 0; r < 4; ++r)
                            if (rk0w + nb*16 + quad*4 + r > relq) s[nb][r] = -1e30f;
                }

                // ---- local 16-max (tree; clang fuses to v_max3) ----
                float a0 = fmaxf(fmaxf(s[0][0], s[0][1]), fmaxf(s[0][2], s[0][3]));
                float a1 = fmaxf(fmaxf(s[1][0], s[1][1]), fmaxf(s[1][2], s[1][3]));
                float a2 = fmaxf(fmaxf(s[2][0], s[2][1]), fmaxf(s[2][2], s[2][3]));
                float a3 = fmaxf(fmaxf(s[3][0], s[3][1]), fmaxf(s[3][2], s[3][3]));
                const float lmax = fmaxf(fmaxf(a0, a1), fmaxf(a2, a3));

                // ---- T13 defer-max: reduce+rescale only when the max actually grew ----
                if (!__all(lmax <= m_s + DEFER_THR)) {
                    float rmax = fmaxf(lmax, __shfl_xor(lmax, 16));
                    rmax = fmaxf(rmax, __shfl_xor(rmax, 32));
                    const float mnew = fmaxf(m_s, rmax);
                    const float cf   = __builtin_amdgcn_exp2f(m_s - mnew);
                    m_s = mnew;
                    l_p *= cf;
                    #pragma unroll
                    for (int nb = 0; nb < 4; ++nb)
                        #pragma unroll
                        for (int r = 0; r < 4; ++r) oacc[nb][r] *= cf;
                }

                // ---- exp2 + partial row-sum (pairwise trees) ----
                float ps[4];
                #pragma unroll
                for (int nb = 0; nb < 4; ++nb) {
                    const float p0 = __builtin_amdgcn_exp2f(s[nb][0] - m_s);
                    const float p1 = __builtin_amdgcn_exp2f(s[nb][1] - m_s);
                    const float p2 = __builtin_amdgcn_exp2f(s[nb][2] - m_s);
                    const float p3 = __builtin_amdgcn_exp2f(s[nb][3] - m_s);
                    s[nb][0]=p0; s[nb][1]=p1; s[nb][2]=p2; s[nb][3]=p3;
                    ps[nb] = (p0 + p1) + (p2 + p3);
                }
                l_p += (ps[0] + ps[1]) + (ps[2] + ps[3]);

                // ---- P -> Pl (uint2 pk stores), read back as B-fragment ----
                #pragma unroll
                for (int nb = 0; nb < 4; ++nb)
                    *(uint2*)(&Pl[w][l16][nb*16 + quad*4]) =
                        make_uint2(cvt2(s[nb][0], s[nb][1]), cvt2(s[nb][2], s[nb][3]));
                bf16x8 pfrag[2];
                #pragma unroll
                for (int kk = 0; kk < 2; ++kk)
                    pfrag[kk] = *(const bf16x8*)(&Pl[w][l16][kk*32 + quad*8]);

                // ---- O^T += V^T P^T : A = Vt rows (dv), B = P cols (q=l16) ----
                __builtin_amdgcn_s_setprio(1);
                #pragma unroll
                for (int nb = 0; nb < 4; ++nb) {
                    #pragma unroll
                    for (int kk = 0; kk < 2; ++kk) {
                        bf16x8 vf = *(const bf16x8*)(&Vt[cur][nb*16 + l16][kk*32 + quad*8]);
                        oacc[nb] = __builtin_amdgcn_mfma_f32_16x16x32_bf16(vf, pfrag[kk], oacc[nb], 0, 0, 0);
                    }
                }
                __builtin_amdgcn_s_setprio(0);
            }

            // ---- write prefetched tile to other buffer; one barrier/tile ----
            if (pf_on) {
                #pragma unroll
                for (int i = 0; i < 2; ++i) {
                    *(uint2*)(&Kl[cur^1][krow + 32*i][kc4]) =
                        make_uint2(cvt2(kpf[i].x,kpf[i].y), cvt2(kpf[i].z,kpf[i].w));
                    Vt[cur^1][vc0+32*i+0][vrow] = cvt1(vpf[i].x);
                    Vt[cur^1][vc0+32*i+1][vrow] = cvt1(vpf[i].y);
                    Vt[cur^1][vc0+32*i+2][vrow] = cvt1(vpf[i].z);
                    Vt[cur^1][vc0+32*i+3][vrow] = cvt1(vpf[i].w);
                }
                kpt += KVBLK * (NHKV*HD);
                vpt += KVBLK * (NHKV*HD);
                __syncthreads();
                cur ^= 1;
            }
        }

        // ---- epilogue: reduce l across quads; O^T store, float4, lane-local ----
        l_p += __shfl_xor(l_p, 16);
        l_p += __shfl_xor(l_p, 32);
        const float inv = 1.0f / l_p;

        float* ob = Ohead + (size_t)(q0 + relq) * HD;
        #pragma unroll
        for (int nb = 0; nb < 4; ++nb) {
            float4 o4;
            o4.x = oacc[nb][0] * inv;
            o4.y = oacc[nb][1] * inv;
            o4.z = oacc[nb][2] * inv;
            o4.w = oacc[nb][3] * inv;
            *(float4*)(ob + nb*16 + quad*4) = o4;
        }
    }
}

extern "C" void kernel_launch(void* const* d_in, const int* in_sizes, int n_in,
                              void* d_out, int out_size, void* d_ws, size_t ws_size,
                              hipStream_t stream) {
    const float* Q = (const float*)d_in[0];
    const float* K = (const float*)d_in[1];
    const float* V = (const float*)d_in[2];
    // d_in[3] (tril mask) computed analytically, never read.
    float* O = (float*)d_out;
    gqa_fwd_kernel<<<dim3(256), dim3(512), 0, stream>>>(Q, K, V, O);
}